// Round 20
// baseline (120.984 us; speedup 1.0000x reference)
//
#include <hip/hip_runtime.h>
#include <stdint.h>
#include <stddef.h>

// BinarizeLinearWithFoldedBN on MI355X (gfx950).
// out[b,o] = dot(sign(x[b,:]), sign(w[o,:])) * scale[o] + bias[o]
//   scale = gamma/sqrt(var+eps), bias = beta - mean*scale (exact BN algebra)
// R20: GEMM = R19 verbatim (R13 structure, BN folded in epilogue; 75.2 us,
//   MfmaUtil 36.5%, 0 conflicts). Pack = LDS-bounce: lane-consecutive reads
//   (1KB/wave-instr, MLP=8) -> u16 nibbles -> LDS -> barrier -> ONE coalesced
//   uint4 store per thread. Both global sides coalesced, 9 vmem instr/128B.
// FP4 (+/-1 e2m1) via v_mfma_f32_16x16x128_f8f6f4 cbsz:4 blgp:4; 256x256
// tile, 16 waves, 4-buf 64B-slab rotation, distance-3 prefetch, counted
// vmcnt, T1 XCD swizzle + T2 granule involution + T5 setprio. Exact f32
// accumulation of +/-1 products.

#define BN_EPS 1e-5f
typedef int   v4i __attribute__((ext_vector_type(4)));
typedef float v4f __attribute__((ext_vector_type(4)));
typedef unsigned int u32;

// ---------------- LDS-bounce pack: f32 signs -> fp4 e2m1 +/-1 nibbles ----------
// Block owns 2048 contiguous uint4 (32 KB in -> 4 KB out).
// Phase 1: 8 coalesced loads u[j] = src[base + j*256 + tid] (1KB/wave-instr).
// Phase 2: u16 nibble words (elem i -> nibble i; +1 -> 0x2, -1 -> 0xA) to LDS
//          at input order (2-way bank aliasing = free).
// Phase 3: thread stores LDS u16[tid*8..tid*8+7] (input-consecutive) as one
//          uint4 to dst[cb*256 + tid] (coalesced; layout bit-identical to R19).
__global__ __launch_bounds__(256) void pack_sign_fp4_lds(
    const uint4* __restrict__ x, uint4* __restrict__ a4, int nblkx,
    const uint4* __restrict__ w, uint4* __restrict__ b4) {
  __shared__ __align__(16) unsigned short sh[2048];
  const int tid = threadIdx.x;
  const int b = blockIdx.x;
  const bool isx = (b < nblkx);                  // block-uniform select
  const uint4* src = isx ? x : w;
  uint4* dst = isx ? a4 : b4;
  const int cb = isx ? b : b - nblkx;
  const size_t base = (size_t)cb * 2048;

  uint4 u[8];
#pragma unroll
  for (int j = 0; j < 8; ++j) u[j] = src[base + j * 256 + tid];
#pragma unroll
  for (int j = 0; j < 8; ++j) {
    unsigned short v = (unsigned short)(0x2222u
        | ((u[j].x >> 28) & 0x8u)        // sign(e0) -> nibble0 bit3
        | ((u[j].y >> 24) & 0x80u)       // sign(e1) -> nibble1 bit3
        | ((u[j].z >> 20) & 0x800u)      // sign(e2) -> nibble2 bit3
        | ((u[j].w >> 16) & 0x8000u));   // sign(e3) -> nibble3 bit3
    sh[j * 256 + tid] = v;
  }
  __syncthreads();
  dst[(size_t)cb * 256 + tid] = *reinterpret_cast<const uint4*>(&sh[tid * 8]);
}

// ---------------- fp4 MFMA GEMM (R19 verbatim; BN folded in epilogue) ----------
// Row bytes RB = IN/2. LDS (128 KiB): A slab buf q (q=0..3): q*16384 (256 x 64 B);
// B slab buf q: 65536 + q*16384. One slab = 64 B/row = K=128 = one MFMA k-step.
// T2 granule involution: LDS(row R, chunk C) = global granule C ^ ((R>>1)&3);
//   write: linear gload_lds dest + pre-swizzled SOURCE granule;
//   read: chunk = (lane>>4) ^ ((ln15>>1)&3)   [0 conflicts, measured].

#define BAR() asm volatile("s_barrier" ::: "memory")
#define WAITV(n) asm volatile("s_waitcnt vmcnt(" #n ")" ::: "memory")
#define LGKM0() asm volatile("s_waitcnt lgkmcnt(0)" ::: "memory")

// fp4 (cbsz:4 / blgp:4): A and B are 4-dword register tuples; acc = 4 x f32
#define MFMA16x16(accv, av, bv) \
  asm("v_mfma_f32_16x16x128_f8f6f4 %0, %1, %2, %0 cbsz:4 blgp:4" \
      : "+v"(accv) : "v"(av), "v"(bv))

__global__ __launch_bounds__(1024, 4) void bgemm_fp4_w16(
    const int8_t* __restrict__ A4, const int8_t* __restrict__ B4,
    const float* __restrict__ gm, const float* __restrict__ bt,
    const float* __restrict__ mn, const float* __restrict__ vr,
    float* __restrict__ out, int M, int N, int RB /* = IN/2 bytes per row */) {
  __shared__ __align__(16) int8_t lds[131072];

  const int tid = threadIdx.x;
  const int lane = tid & 63;
  const int wid = tid >> 6;      // 0..15
  const int wm = wid >> 2;       // 0..3  (64-row band)
  const int wn = wid & 3;        // 0..3  (64-col band)

  // T1: bijective XCD swizzle (nwg % 8 == 0 here: 32*16 = 512)
  const int nbx = N >> 8;
  const int nwg = (M >> 8) * nbx;
  const int cpx = nwg >> 3;
  const int bid = (int)blockIdx.x;
  const int swz = (bid & 7) * cpx + (bid >> 3);
  const int row0 = (swz / nbx) << 8;
  const int col0 = (swz % nbx) << 8;

  const int ln15 = lane & 15;
  // T2 read-side swizzle (verified): chunk byte offset
  const int kcs = (((lane >> 4) ^ ((ln15 >> 1) & 3)) << 4);
  const int aoff = (wm * 64 + ln15) * 64 + kcs;    // + m*1024, m=0..3
  const int boff = (wn * 64 + ln15) * 64 + kcs;    // + n*1024, n=0..3

  // staging: wave wid stages rows wid*16..wid*16+15 of A and of B (1 KB each)
  const int srow = wid * 16 + (lane >> 2);
  const int sch = (((lane & 3) ^ ((lane >> 3) & 3)) << 4);  // pre-swizzled source granule
  const int ldw = wid << 10;                // wave slot: 1 KB

  const int8_t* aSt = A4 + (size_t)(row0 + srow) * RB + sch;
  const int8_t* bSt = B4 + (size_t)(col0 + srow) * RB + sch;

  v4f acc[4][4];
#pragma unroll
  for (int i = 0; i < 4; ++i)
#pragma unroll
    for (int n = 0; n < 4; ++n) { v4f z = {0.f, 0.f, 0.f, 0.f}; acc[i][n] = z; }

// 2 global_load_lds per wave per slab (A row-group + B row-group)
#define STAGE(s) do {                                                                 \
  const int bb_ = ((s) & 3) * 16384;                                                  \
  __builtin_amdgcn_global_load_lds(                                                   \
      (const __attribute__((address_space(1))) uint32_t*)(aSt + (size_t)(s) * 64),    \
      (__attribute__((address_space(3))) uint32_t*)(lds + bb_ + ldw), 16, 0, 0);      \
  __builtin_amdgcn_global_load_lds(                                                   \
      (const __attribute__((address_space(1))) uint32_t*)(bSt + (size_t)(s) * 64),    \
      (__attribute__((address_space(3))) uint32_t*)(lds + 65536 + bb_ + ldw), 16, 0, 0); \
} while (0)

// one K=128 slab from buf q: 4 B reads (reused by 4 m-tiles) + per-m A read
// + 4 MFMAs. Register deps give the compiler counted lgkmcnt under the MFMAs.
#define COMPUTE(q) do {                                                               \
  const int8_t* ap_ = lds + (q) * 16384 + aoff;                                       \
  const int8_t* bp_ = lds + 65536 + (q) * 16384 + boff;                               \
  v4i Bv0 = *(const v4i*)(bp_);        v4i Bv1 = *(const v4i*)(bp_ + 1024);           \
  v4i Bv2 = *(const v4i*)(bp_ + 2048); v4i Bv3 = *(const v4i*)(bp_ + 3072);           \
  __builtin_amdgcn_s_setprio(1);                                                      \
  _Pragma("unroll")                                                                   \
  for (int m_ = 0; m_ < 4; ++m_) {                                                    \
    v4i Av = *(const v4i*)(ap_ + m_ * 1024);                                          \
    MFMA16x16(acc[m_][0], Av, Bv0);                                                   \
    MFMA16x16(acc[m_][1], Av, Bv1);                                                   \
    MFMA16x16(acc[m_][2], Av, Bv2);                                                   \
    MFMA16x16(acc[m_][3], Av, Bv3);                                                   \
  }                                                                                   \
  __builtin_amdgcn_s_setprio(0);                                                      \
} while (0)

  const int NT = RB >> 6;   // 64-byte slabs (K=128 each); 32 for IN=4096

  // ---- prologue: prefetch slabs 0,1,2 (6 loads); certify slab 0 (4 left); BAR
  STAGE(0); STAGE(1); STAGE(2);
  WAITV(4);
  BAR();

  // ---- main loop: compute slab t, stage slab t+3 into buf (t+3)&3 = (t-1)&3,
  // whose readers drained at body t-1's LGKM0+BAR.
  for (int t = 0; t < NT - 3; ++t) {
    STAGE(t + 3);     // outstanding: slabs t+1,t+2,t+3 = 6 loads
    COMPUTE(t & 3);
    LGKM0();          // my LDS reads of buf t&3 done -> reusable after BAR
    WAITV(4);         // slab t+1's 2 loads retired (6 -> 4)
    BAR();            // certifies both for every wave
  }
  // tail: drain 4 -> 2 -> 0
  COMPUTE((NT - 3) & 3); LGKM0(); WAITV(2); BAR();
  COMPUTE((NT - 2) & 3); LGKM0(); WAITV(0); BAR();
  COMPUTE((NT - 1) & 3);
  asm volatile("s_nop 7\n\ts_nop 7" :::);   // MFMA write -> VALU read hazard guard

  // ---- epilogue: 16x16 C/D layout: col = lane&15, row = (lane>>4)*4 + reg
  // (verified). acc[i] <-> rows wm*64 + i*16. BN folded inline (exact algebra).
  const int cw = col0 + wn * 64;
  float scv[4], biv[4];
#pragma unroll
  for (int n = 0; n < 4; ++n) {
    int c = cw + n * 16 + ln15;
    float s = gm[c] * rsqrtf(vr[c] + BN_EPS);
    scv[n] = s;
    biv[n] = bt[c] - mn[c] * s;
  }
#pragma unroll
  for (int i = 0; i < 4; ++i) {
    const int r0 = row0 + wm * 64 + i * 16 + ((lane >> 4) << 2);
#pragma unroll
    for (int reg = 0; reg < 4; ++reg) {
      float* orow = out + (size_t)(r0 + reg) * N;
#pragma unroll
      for (int n = 0; n < 4; ++n)
        orow[cw + n * 16 + ln15] = fmaf(acc[i][n][reg], scv[n], biv[n]);
    }
  }

#undef STAGE
#undef COMPUTE
}

// ======================= launch =======================
extern "C" void kernel_launch(void* const* d_in, const int* in_sizes, int n_in,
                              void* d_out, int out_size, void* d_ws, size_t ws_size,
                              hipStream_t stream) {
  const float* x = (const float*)d_in[0];
  const float* w = (const float*)d_in[1];
  const float* gamma = (const float*)d_in[2];
  const float* beta = (const float*)d_in[3];
  const float* mean = (const float*)d_in[4];
  const float* var = (const float*)d_in[5];
  float* out = (float*)d_out;

  const int OUT = in_sizes[2];            // 4096
  const int IN = in_sizes[1] / OUT;       // 4096
  const int B = in_sizes[0] / IN;         // 8192
  const int RB = IN / 2;                  // packed fp4 bytes per row

  int8_t* a4 = (int8_t*)d_ws;
  int8_t* b4 = a4 + (size_t)B * RB;

  // one fused pack launch: block = 8192 floats (32 KB in -> 4 KB out)
  const int nblkx = B * (IN / 32) / 256;   // 4096 blocks for x (exact)
  const int nblkw = OUT * (IN / 32) / 256; // 2048 blocks for w (exact)
  pack_sign_fp4_lds<<<nblkx + nblkw, 256, 0, stream>>>(
      (const uint4*)x, (uint4*)a4, nblkx,
      (const uint4*)w, (uint4*)b4);

  dim3 grid((B >> 8) * (OUT >> 8));
  bgemm_fp4_w16<<<grid, 1024, 0, stream>>>(
      a4, b4, gamma, beta, mean, var, out, B, OUT, RB);
}

// Round 21
// 116.594 us; speedup vs baseline: 1.0377x; 1.0377x over previous
//
#include <hip/hip_runtime.h>
#include <stdint.h>
#include <stddef.h>

// BinarizeLinearWithFoldedBN on MI355X (gfx950).
// out[b,o] = dot(sign(x[b,:]), sign(w[o,:])) * scale[o] + bias[o]
//   scale = gamma/sqrt(var+eps), bias = beta - mean*scale (exact BN algebra)
// R21 = R19 (best measured: 120.2 us total) + nontemporal C-stores in the
// GEMM epilogue (keep A/B panels L2-resident against the 131 MB C-stream).
//   1) fused pack: 8 uint4 loads MLP=8, ONE 16B store per 128B input,
//      block-uniform x/w select.
//   2) GEMM: R13 structure (75.2 us, MfmaUtil 36.5%, 0 bank conflicts),
//      BN folded into the epilogue.
// FP4 (+/-1 e2m1) via v_mfma_f32_16x16x128_f8f6f4 cbsz:4 blgp:4; 256x256
// tile, 16 waves, 4-buf 64B-slab rotation, distance-3 prefetch, counted
// vmcnt, T1 XCD swizzle + T2 granule involution + T5 setprio. Exact f32
// accumulation of +/-1 products.

#define BN_EPS 1e-5f
typedef int   v4i __attribute__((ext_vector_type(4)));
typedef float v4f __attribute__((ext_vector_type(4)));
typedef unsigned int u32;

// ---------------- fused pack: f32 signs -> fp4 e2m1 +/-1 nibbles ----------------
// +1 -> 0x2, -1 -> 0xA. Thread handles 8 uint4 (32 floats) -> one 16B store.
// Blocks [0, nblkx) pack x -> a4; blocks [nblkx, nblkx+nblkw) pack w -> b4.
__global__ __launch_bounds__(256) void pack_sign_fp4_fused(
    const uint4* __restrict__ x, uint4* __restrict__ a4, int nblkx,
    const uint4* __restrict__ w, uint4* __restrict__ b4) {
  const int b = blockIdx.x;
  const bool isx = (b < nblkx);                  // block-uniform select
  const uint4* src = isx ? x : w;
  uint4* dst = isx ? a4 : b4;
  const int t = (isx ? b : b - nblkx) * 256 + (int)threadIdx.x;

  const uint4* p = src + (size_t)t * 8;
  u32 wd[4];
#pragma unroll
  for (int j = 0; j < 4; ++j) {
    uint4 u0 = p[2 * j];
    uint4 u1 = p[2 * j + 1];
    u32 h0 = 0x2222u | ((u0.x >> 28) & 0x8u) | (((u0.y >> 28) & 0x8u) << 4)
                     | (((u0.z >> 28) & 0x8u) << 8) | (((u0.w >> 28) & 0x8u) << 12);
    u32 h1 = 0x2222u | ((u1.x >> 28) & 0x8u) | (((u1.y >> 28) & 0x8u) << 4)
                     | (((u1.z >> 28) & 0x8u) << 8) | (((u1.w >> 28) & 0x8u) << 12);
    wd[j] = h0 | (h1 << 16);
  }
  uint4 o; o.x = wd[0]; o.y = wd[1]; o.z = wd[2]; o.w = wd[3];
  dst[t] = o;
}

// ---------------- fp4 MFMA GEMM (R13 structure; BN folded; nt C-stores) ---------
// Row bytes RB = IN/2. LDS (128 KiB): A slab buf q (q=0..3): q*16384 (256 x 64 B);
// B slab buf q: 65536 + q*16384. One slab = 64 B/row = K=128 = one MFMA k-step.
// T2 granule involution: LDS(row R, chunk C) = global granule C ^ ((R>>1)&3);
//   write: linear gload_lds dest + pre-swizzled SOURCE granule;
//   read: chunk = (lane>>4) ^ ((ln15>>1)&3)   [0 conflicts, measured].

#define BAR() asm volatile("s_barrier" ::: "memory")
#define WAITV(n) asm volatile("s_waitcnt vmcnt(" #n ")" ::: "memory")
#define LGKM0() asm volatile("s_waitcnt lgkmcnt(0)" ::: "memory")

// fp4 (cbsz:4 / blgp:4): A and B are 4-dword register tuples; acc = 4 x f32
#define MFMA16x16(accv, av, bv) \
  asm("v_mfma_f32_16x16x128_f8f6f4 %0, %1, %2, %0 cbsz:4 blgp:4" \
      : "+v"(accv) : "v"(av), "v"(bv))

__global__ __launch_bounds__(1024, 4) void bgemm_fp4_w16(
    const int8_t* __restrict__ A4, const int8_t* __restrict__ B4,
    const float* __restrict__ gm, const float* __restrict__ bt,
    const float* __restrict__ mn, const float* __restrict__ vr,
    float* __restrict__ out, int M, int N, int RB /* = IN/2 bytes per row */) {
  __shared__ __align__(16) int8_t lds[131072];

  const int tid = threadIdx.x;
  const int lane = tid & 63;
  const int wid = tid >> 6;      // 0..15
  const int wm = wid >> 2;       // 0..3  (64-row band)
  const int wn = wid & 3;        // 0..3  (64-col band)

  // T1: bijective XCD swizzle (nwg % 8 == 0 here: 32*16 = 512)
  const int nbx = N >> 8;
  const int nwg = (M >> 8) * nbx;
  const int cpx = nwg >> 3;
  const int bid = (int)blockIdx.x;
  const int swz = (bid & 7) * cpx + (bid >> 3);
  const int row0 = (swz / nbx) << 8;
  const int col0 = (swz % nbx) << 8;

  const int ln15 = lane & 15;
  // T2 read-side swizzle (verified): chunk byte offset
  const int kcs = (((lane >> 4) ^ ((ln15 >> 1) & 3)) << 4);
  const int aoff = (wm * 64 + ln15) * 64 + kcs;    // + m*1024, m=0..3
  const int boff = (wn * 64 + ln15) * 64 + kcs;    // + n*1024, n=0..3

  // staging: wave wid stages rows wid*16..wid*16+15 of A and of B (1 KB each)
  const int srow = wid * 16 + (lane >> 2);
  const int sch = (((lane & 3) ^ ((lane >> 3) & 3)) << 4);  // pre-swizzled source granule
  const int ldw = wid << 10;                // wave slot: 1 KB

  const int8_t* aSt = A4 + (size_t)(row0 + srow) * RB + sch;
  const int8_t* bSt = B4 + (size_t)(col0 + srow) * RB + sch;

  v4f acc[4][4];
#pragma unroll
  for (int i = 0; i < 4; ++i)
#pragma unroll
    for (int n = 0; n < 4; ++n) { v4f z = {0.f, 0.f, 0.f, 0.f}; acc[i][n] = z; }

// 2 global_load_lds per wave per slab (A row-group + B row-group)
#define STAGE(s) do {                                                                 \
  const int bb_ = ((s) & 3) * 16384;                                                  \
  __builtin_amdgcn_global_load_lds(                                                   \
      (const __attribute__((address_space(1))) uint32_t*)(aSt + (size_t)(s) * 64),    \
      (__attribute__((address_space(3))) uint32_t*)(lds + bb_ + ldw), 16, 0, 0);      \
  __builtin_amdgcn_global_load_lds(                                                   \
      (const __attribute__((address_space(1))) uint32_t*)(bSt + (size_t)(s) * 64),    \
      (__attribute__((address_space(3))) uint32_t*)(lds + 65536 + bb_ + ldw), 16, 0, 0); \
} while (0)

// one K=128 slab from buf q: 4 B reads (reused by 4 m-tiles) + per-m A read
// + 4 MFMAs. Register deps give the compiler counted lgkmcnt under the MFMAs.
#define COMPUTE(q) do {                                                               \
  const int8_t* ap_ = lds + (q) * 16384 + aoff;                                       \
  const int8_t* bp_ = lds + 65536 + (q) * 16384 + boff;                               \
  v4i Bv0 = *(const v4i*)(bp_);        v4i Bv1 = *(const v4i*)(bp_ + 1024);           \
  v4i Bv2 = *(const v4i*)(bp_ + 2048); v4i Bv3 = *(const v4i*)(bp_ + 3072);           \
  __builtin_amdgcn_s_setprio(1);                                                      \
  _Pragma("unroll")                                                                   \
  for (int m_ = 0; m_ < 4; ++m_) {                                                    \
    v4i Av = *(const v4i*)(ap_ + m_ * 1024);                                          \
    MFMA16x16(acc[m_][0], Av, Bv0);                                                   \
    MFMA16x16(acc[m_][1], Av, Bv1);                                                   \
    MFMA16x16(acc[m_][2], Av, Bv2);                                                   \
    MFMA16x16(acc[m_][3], Av, Bv3);                                                   \
  }                                                                                   \
  __builtin_amdgcn_s_setprio(0);                                                      \
} while (0)

  const int NT = RB >> 6;   // 64-byte slabs (K=128 each); 32 for IN=4096

  // ---- prologue: prefetch slabs 0,1,2 (6 loads); certify slab 0 (4 left); BAR
  STAGE(0); STAGE(1); STAGE(2);
  WAITV(4);
  BAR();

  // ---- main loop: compute slab t, stage slab t+3 into buf (t+3)&3 = (t-1)&3,
  // whose readers drained at body t-1's LGKM0+BAR.
  for (int t = 0; t < NT - 3; ++t) {
    STAGE(t + 3);     // outstanding: slabs t+1,t+2,t+3 = 6 loads
    COMPUTE(t & 3);
    LGKM0();          // my LDS reads of buf t&3 done -> reusable after BAR
    WAITV(4);         // slab t+1's 2 loads retired (6 -> 4)
    BAR();            // certifies both for every wave
  }
  // tail: drain 4 -> 2 -> 0
  COMPUTE((NT - 3) & 3); LGKM0(); WAITV(2); BAR();
  COMPUTE((NT - 2) & 3); LGKM0(); WAITV(0); BAR();
  COMPUTE((NT - 1) & 3);
  asm volatile("s_nop 7\n\ts_nop 7" :::);   // MFMA write -> VALU read hazard guard

  // ---- epilogue: 16x16 C/D layout: col = lane&15, row = (lane>>4)*4 + reg
  // (verified). acc[i] <-> rows wm*64 + i*16. BN folded inline (exact algebra).
  // NONTEMPORAL stores: the 131 MB C-stream must not evict A/B panels from L2.
  const int cw = col0 + wn * 64;
  float scv[4], biv[4];
#pragma unroll
  for (int n = 0; n < 4; ++n) {
    int c = cw + n * 16 + ln15;
    float s = gm[c] * rsqrtf(vr[c] + BN_EPS);
    scv[n] = s;
    biv[n] = bt[c] - mn[c] * s;
  }
#pragma unroll
  for (int i = 0; i < 4; ++i) {
    const int r0 = row0 + wm * 64 + i * 16 + ((lane >> 4) << 2);
#pragma unroll
    for (int reg = 0; reg < 4; ++reg) {
      float* orow = out + (size_t)(r0 + reg) * N;
#pragma unroll
      for (int n = 0; n < 4; ++n)
        __builtin_nontemporal_store(
            fmaf(acc[i][n][reg], scv[n], biv[n]),
            orow + cw + n * 16 + ln15);
    }
  }

#undef STAGE
#undef COMPUTE
}

// ======================= launch =======================
extern "C" void kernel_launch(void* const* d_in, const int* in_sizes, int n_in,
                              void* d_out, int out_size, void* d_ws, size_t ws_size,
                              hipStream_t stream) {
  const float* x = (const float*)d_in[0];
  const float* w = (const float*)d_in[1];
  const float* gamma = (const float*)d_in[2];
  const float* beta = (const float*)d_in[3];
  const float* mean = (const float*)d_in[4];
  const float* var = (const float*)d_in[5];
  float* out = (float*)d_out;

  const int OUT = in_sizes[2];            // 4096
  const int IN = in_sizes[1] / OUT;       // 4096
  const int B = in_sizes[0] / IN;         // 8192
  const int RB = IN / 2;                  // packed fp4 bytes per row

  int8_t* a4 = (int8_t*)d_ws;
  int8_t* b4 = a4 + (size_t)B * RB;

  // one fused pack launch: thread = 32 floats; block = 8192 floats
  const int nblkx = B * (IN / 32) / 256;   // 4096 blocks for x (exact)
  const int nblkw = OUT * (IN / 32) / 256; // 2048 blocks for w (exact)
  pack_sign_fp4_fused<<<nblkx + nblkw, 256, 0, stream>>>(
      (const uint4*)x, (uint4*)a4, nblkx,
      (const uint4*)w, (uint4*)b4);

  dim3 grid((B >> 8) * (OUT >> 8));
  bgemm_fp4_w16<<<grid, 1024, 0, stream>>>(
      a4, b4, gamma, beta, mean, var, out, B, OUT, RB);
}